// Round 10
// baseline (214.641 us; speedup 1.0000x reference)
//
#include <hip/hip_runtime.h>
#include <hip/hip_bf16.h>

typedef __hip_bfloat16 bf16;
typedef unsigned long long u64;
typedef __attribute__((ext_vector_type(8))) short short8;   // 8 bf16 = MFMA A/B frag
typedef __attribute__((ext_vector_type(4))) float f32x4;    // MFMA C/D frag

#define B_   2
#define C_   128
#define T_   32
#define N_   512
#define K_   16
#define HID_ 512
#define TN   (T_*N_)          // 16384
#define PTS  (B_*T_*N_)       // 32768

#define MFMA_BF16(a,b,c) __builtin_amdgcn_mfma_f32_16x16x32_bf16((a),(b),(c),0,0,0)

__device__ __forceinline__ float b2f(bf16 v){ return __bfloat162float(v); }
__device__ __forceinline__ bf16  f2b(float v){ return __float2bfloat16(v); }
__device__ __forceinline__ float bqf(short v){            // bf16 bits -> f32 (exact)
  return __uint_as_float(((unsigned)(unsigned short)v) << 16);
}

__device__ __forceinline__ float ldc(const void* p, int i, bool f32) {
  return f32 ? ((const float*)p)[i] : b2f(((const bf16*)p)[i]);
}

// ---------- convert weights + bn; every block locally detects input dtype; blk0 publishes flag ----------
__global__ __launch_bounds__(256) void convw_kernel(
    const void* __restrict__ x,
    const void* wq, const void* wk, const void* wv,
    const void* w1, const void* w2, const void* g, const void* bb,
    const void* m, const void* v,
    bf16* __restrict__ wqb, bf16* __restrict__ wkb, bf16* __restrict__ wvb,
    bf16* __restrict__ w1b, bf16* __restrict__ w2b,
    float* __restrict__ gf, float* __restrict__ bf_, float* __restrict__ mf,
    float* __restrict__ vf, int* __restrict__ flag)
{
  __shared__ int cnt;
  if (threadIdx.x == 0) cnt = 0;
  __syncthreads();
  const unsigned short* u = (const unsigned short*)x;
  int w = 0;
#pragma unroll
  for (int j = 0; j < 8; ++j) {
    unsigned short hv = u[threadIdx.x*8 + j];
    int e = (hv >> 7) & 0xFF;
    if (e >= 0x89) w++;
  }
  if (w) atomicAdd(&cnt, w);
  __syncthreads();
  bool f32 = (cnt > 32);
  if (blockIdx.x == 0 && threadIdx.x == 0) *flag = f32 ? 1 : 0;

  int i = blockIdx.x*256 + threadIdx.x;            // grid covers 180736 exactly
  if (i < 16384) { wqb[i] = f2b(ldc(wq, i, f32)); return; } i -= 16384;
  if (i < 16384) { wkb[i] = f2b(ldc(wk, i, f32)); return; } i -= 16384;
  if (i < 16384) { wvb[i] = f2b(ldc(wv, i, f32)); return; } i -= 16384;
  if (i < 65536) { w1b[i] = f2b(ldc(w1, i, f32)); return; } i -= 65536;
  if (i < 65536) { w2b[i] = f2b(ldc(w2, i, f32)); return; } i -= 65536;
  if (i < 128)   { gf[i]  = ldc(g, i, f32); return; }       i -= 128;
  if (i < 128)   { bf_[i] = ldc(bb, i, f32); return; }      i -= 128;
  if (i < 128)   { mf[i]  = ldc(m, i, f32); return; }       i -= 128;
  if (i < 128)   { vf[i]  = ldc(v, i, f32); return; }
}

// ---------- bitonic helpers ----------
__device__ __forceinline__ u64 shflx64(u64 v, int m) {
  return (u64)__shfl_xor((long long)v, m, 64);
}
template<int W>
__device__ __forceinline__ u64 bitonic64w(u64 key, int lane) {
#pragma unroll
  for (int k = 2; k <= W; k <<= 1) {
#pragma unroll
    for (int j = k >> 1; j >= 1; j >>= 1) {
      u64 p = shflx64(key, j);
      bool keep_min = ((lane & k) == 0) == ((lane & j) == 0);
      key = ((p < key) == keep_min) ? p : key;
    }
  }
  return key;
}
__device__ __forceinline__ unsigned bitonic32u(unsigned key, int lane) {
#pragma unroll
  for (int k = 2; k <= 64; k <<= 1) {
#pragma unroll
    for (int j = k >> 1; j >= 1; j >>= 1) {
      unsigned p = (unsigned)__shfl_xor((int)key, j, 64);
      bool keep_min = ((lane & k) == 0) == ((lane & j) == 0);
      key = ((p < key) == keep_min) ? p : key;
    }
  }
  return key;
}

// ---------- MFMA GEMM helper (8-wave variant): wave owns one 16-col otile ----------
__device__ __forceinline__ void proj_gemm8(const bf16* __restrict__ W,
                                           bf16 (*ys)[136],
                                           const short8 am[4][4],
                                           int mrow, int quad, int ot)
{
  f32x4 acc[4];
#pragma unroll
  for (int mt=0;mt<4;++mt) acc[mt] = (f32x4){0.f,0.f,0.f,0.f};
#pragma unroll
  for (int kq=0;kq<4;++kq) {
    short8 bfr = *(const short8*)&W[(ot*16+mrow)*C_ + kq*32 + quad*8];
#pragma unroll
    for (int mt=0;mt<4;++mt) acc[mt] = MFMA_BF16(am[mt][kq], bfr, acc[mt]);
  }
#pragma unroll
  for (int mt=0;mt<4;++mt)
#pragma unroll
    for (int r=0;r<4;++r)
      ys[mt*16 + quad*4 + r][ot*16 + mrow] = f2b(acc[mt][r]);
}

__device__ __forceinline__ void tile_store128_512(bf16* __restrict__ dst,
                                                  const bf16 (*ys)[136], int tid)
{
#pragma unroll
  for (int it=0; it<2; ++it) {
    int flat = (it*512 + tid)*8;
    int p = flat >> 7, c = flat & 127;
    *(short8*)&dst[(size_t)p*C_ + c] = *(const short8*)&ys[p][c];
  }
}

// ---------- FUSED proj + knn: independent block types co-resident (both read only x) ----------
// blk%9==8 -> proj block (512 of them); else knn block (4096). Interleaved so both
// types co-schedule from t=0: knn is VALU/DS-bound, proj is MFMA/VMEM-bound.
__global__ __launch_bounds__(512) void projknn_kernel(
    const void* __restrict__ x, const int* __restrict__ flag,
    const bf16* __restrict__ wqb, const bf16* __restrict__ wkb, const bf16* __restrict__ wvb,
    bf16* __restrict__ xTb, bf16* QT, bf16* __restrict__ KT, bf16* __restrict__ VT,
    int* __restrict__ idxout)
{
  __shared__ __align__(16) char smem[52224];       // union: proj 52.2KB | knn 28.7KB
  int tid = threadIdx.x;
  int blk = blockIdx.x;
  int g = blk / 9, r = blk - g*9;
  if (r == 8) {
    // ================= proj block g ∈ [0,512) =================
    bf16 (*xs )[136] = (bf16(*)[136])(smem);
    bf16 (*ysK)[136] = (bf16(*)[136])(smem + 17408);
    bf16 (*ysV)[136] = (bf16(*)[136])(smem + 34816);
    int p0 = g * 64;
    int b = p0 >> 14; int tn0 = p0 & (TN-1);
    if (*flag) {                                   // f32 inputs
      const float* xbase = (const float*)x + (size_t)b*C_*TN + tn0;
#pragma unroll
      for (int it=0; it<16; ++it) {
        int i = it*512 + tid;
        int c = i >> 6, p = i & 63;                // coalesced over n
        xs[p][c] = f2b(xbase[(size_t)c*TN + p]);
      }
    } else {                                       // bf16 inputs (bit-exact stage)
      const bf16* xbase = (const bf16*)x + (size_t)b*C_*TN + tn0;
#pragma unroll
      for (int it=0; it<16; ++it) {
        int i = it*512 + tid;
        int c = i >> 6, p = i & 63;
        xs[p][c] = xbase[(size_t)c*TN + p];
      }
    }
    __syncthreads();
    tile_store128_512(xTb + (size_t)p0*C_, xs, tid);   // point-major bf16 x
    int lane = tid & 63, wave = tid >> 6;          // 8 waves
    int mrow = lane & 15, quad = lane >> 4;
    short8 am[4][4];                               // A-frags (all 64 points)
#pragma unroll
    for (int mt=0;mt<4;++mt)
#pragma unroll
      for (int kq=0;kq<4;++kq)
        am[mt][kq] = *(const short8*)&xs[mt*16 + mrow][kq*32 + quad*8];
    __syncthreads();                               // xs reads done; xs becomes ysQ
    proj_gemm8(wqb, xs,  am, mrow, quad, wave);
    proj_gemm8(wkb, ysK, am, mrow, quad, wave);
    proj_gemm8(wvb, ysV, am, mrow, quad, wave);
    __syncthreads();
    tile_store128_512(QT + (size_t)p0*C_, xs,  tid);
    tile_store128_512(KT + (size_t)p0*C_, ysK, tid);
    tile_store128_512(VT + (size_t)p0*C_, ysV, tid);
  } else {
    // ================= knn block kblk = g*8+r ∈ [0,4096) =================
    float4* cand4 = (float4*)smem;                 // 24576 B
    u64 (*surv)[64] = (u64(*)[64])(smem + 24576);  // 4096 B
    int kblk = g*8 + r;
    int row = kblk >> 6;                           // (b,t)
    int b = row >> 5, t = row & 31;
    int ng = kblk & 63;
    bool f32 = (*flag != 0);
#pragma unroll
    for (int q = 0; q < 3; ++q) {                  // j=q time slot; 512 cols coalesced
      int tt = t - 1 + q; tt = tt < 0 ? 0 : (tt > T_-1 ? T_-1 : tt);
      size_t base = ((size_t)b*C_*T_ + tt)*(size_t)N_ + tid;   // ch0
      float c0, c1, c2;
      if (f32) {
        const float* xp = (const float*)x;
        c0 = xp[base]; c1 = xp[base + (size_t)T_*N_]; c2 = xp[base + 2*(size_t)T_*N_];
      } else {
        const bf16* xp = (const bf16*)x;
        c0 = b2f(xp[base]); c1 = b2f(xp[base + (size_t)T_*N_]); c2 = b2f(xp[base + 2*(size_t)T_*N_]);
      }
      cand4[q*N_ + tid] = make_float4(c0, c1, c2, 0.f);
    }
    __syncthreads();
    int wave = tid >> 6, lane = tid & 63;
    int n = ng*8 + wave;                           // this wave's point
    float4 a = cand4[N_ + n];                      // self (j=1 slot), broadcast read
    unsigned db[24];                               // lane owns m = lane + 64j
#pragma unroll
    for (int j = 0; j < 24; ++j) {
      float4 cm = cand4[lane + (j << 6)];          // one ds_read_b128, conflict-free
      float dx = a.x - cm.x;
      float dy = a.y - cm.y;
      float dz = a.z - cm.z;
      float d2 = __fadd_rn(__fadd_rn(__fmul_rn(dx,dx), __fmul_rn(dy,dy)), __fmul_rn(dz,dz));
      db[j] = __float_as_uint(d2);                 // d2>=0 -> u32 order == f32 order
    }
    unsigned bd = db[0];
#pragma unroll
    for (int j = 1; j < 24; ++j) bd = (db[j] < bd) ? db[j] : bd;
    unsigned sd = bitonic32u(bd, lane);
    unsigned U = (unsigned)__shfl((int)sd, 15, 64);
    int c = 0;
#pragma unroll
    for (int j = 0; j < 24; ++j) c += (db[j] <= U) ? 1 : 0;
    int sc = c;                                    // inclusive wave prefix sum
#pragma unroll
    for (int d = 1; d < 64; d <<= 1) {
      int pv = __shfl_up(sc, d, 64);
      if (lane >= d) sc += pv;
    }
    int total = __shfl(sc, 63, 64);
    int ofs = sc - c;
    u64 out16;
    if (total <= 64) {                             // ~always (E[total] ~ 18)
#pragma unroll
      for (int j = 0; j < 24; ++j) {
        if (db[j] <= U) {
          surv[wave][ofs] = ((u64)db[j] << 32) | (unsigned)(lane + (j << 6));
          ++ofs;
        }
      }
      __threadfence_block();
      u64 kk = (lane < total) ? surv[wave][lane] : ~0ull;
      out16 = (total <= 32) ? bitonic64w<32>(kk, lane)
                            : bitonic64w<64>(kk, lane); // lanes 0..15 = exact top-16
    } else {
      u64 key[24];                                 // exact fallback (rare)
#pragma unroll
      for (int j = 0; j < 24; ++j)
        key[j] = ((u64)db[j] << 32) | (unsigned)(lane + (j << 6));
      u64 res = ~0ull;
#pragma unroll 1
      for (int rr = 0; rr < 16; ++rr) {
        u64 m2 = key[0];
#pragma unroll
        for (int j = 1; j < 24; ++j) m2 = (key[j] < m2) ? key[j] : m2;
#pragma unroll
        for (int s = 32; s >= 1; s >>= 1) {
          u64 p = shflx64(m2, s);
          m2 = (p < m2) ? p : m2;
        }
        if (lane == rr) res = m2;
        int mwin = (int)(m2 & 0xffffffffu);
        int sel = ((mwin & 63) == lane) ? (mwin >> 6) : -1;
#pragma unroll
        for (int j = 0; j < 24; ++j) if (j == sel) key[j] = ~0ull;
      }
      out16 = res;
    }
    int point = (b*T_ + t)*N_ + n;
    if (lane < K_) idxout[point*K_ + lane] = (int)(out16 & 0xffffffffu);
  }
}

// ---------- attention: 4 points / 512-thread block; vectorized energy phase ----------
__global__ __launch_bounds__(512) void attn_kernel(
    const int* __restrict__ idxin, const bf16* __restrict__ xTb,
    bf16* qhT /* in: QT, out: hT */, const bf16* __restrict__ KT,
    const bf16* __restrict__ VT,
    const float* __restrict__ gf, const float* __restrict__ bf_,
    const float* __restrict__ mf, const float* __restrict__ vf)
{
  __shared__ int   col_lds[4][16];
  __shared__ float qbuf[4][C_];
  __shared__ bf16  kbuf[4][K_][136];
  __shared__ bf16  vbuf[4][K_][136];               // ~38 KB total
  __shared__ float e_lds[4][4][16];
  int tid = threadIdx.x;
  int pt = tid >> 7, o = tid & 127;
  int point = blockIdx.x*4 + pt;
  int b = point >> 14; int tn = point & (TN-1); int t = tn >> 9;
  if (o < K_) {
    int m = idxin[point*K_ + o];
    int j = m >> 9, nn = m & (N_-1);
    int tt = t-1+j; tt = tt<0?0:(tt>T_-1?T_-1:tt);
    col_lds[pt][o] = ((b*T_ + tt)*N_ + nn)*C_;
  }
  int self = point*C_;
  qbuf[pt][o] = b2f(qhT[self + o]);                // QT reads done before first sync
  __syncthreads();
  // gather 64 K/V columns per block as 16B chunks (coalesced 256B per column)
#pragma unroll
  for (int it = 0; it < 2; ++it) {
    int i = it*512 + tid;
    int pp = i >> 8, rem = i & 255, k = rem >> 4, ch = rem & 15;
    int src = col_lds[pp][k] + ch*8;
    *(short8*)&kbuf[pp][k][ch*8] = *(const short8*)&KT[src];
    *(short8*)&vbuf[pp][k][ch*8] = *(const short8*)&VT[src];
  }
  __syncthreads();
  {
    // energies: all 512 threads; thread = (point, k, head, half16)
    int pp = tid >> 7, j = tid & 127;
    int k = j >> 3, hd = (j >> 1) & 3, half = j & 1;
    const float* qp = &qbuf[pp][hd*32 + half*16];
    const bf16*  kp = &kbuf[pp][k][hd*32 + half*16];
    short8 kv0 = *(const short8*)kp;
    short8 kv1 = *(const short8*)(kp + 8);
    float qv[16];
    *(float4*)&qv[0]  = *(const float4*)(qp);
    *(float4*)&qv[4]  = *(const float4*)(qp + 4);
    *(float4*)&qv[8]  = *(const float4*)(qp + 8);
    *(float4*)&qv[12] = *(const float4*)(qp + 12);
    float e = 0.f;
#pragma unroll
    for (int i2=0;i2<8;++i2) e = fmaf(qv[i2],   bqf(kv0[i2]), e);
#pragma unroll
    for (int i2=0;i2<8;++i2) e = fmaf(qv[8+i2], bqf(kv1[i2]), e);
    e += __shfl_xor(e, 1, 64);                     // combine the two halves
    // energy = q.(Kself - Knb)/sqrt(D); self term k-constant -> dropped
    if (!half) e_lds[pp][hd][k] = -e * 0.17677669529663687f;
  }
  __syncthreads();
  int hd = o >> 5;
  float e[16]; float mx = -3e38f;
#pragma unroll
  for (int k=0;k<K_;++k){ e[k]=e_lds[pt][hd][k]; mx=fmaxf(mx,e[k]); }
  float ssum=0.f;
#pragma unroll
  for (int k=0;k<K_;++k){ e[k]=__expf(e[k]-mx); ssum+=e[k]; }
  float inv = 1.f/ssum;
  float acc = b2f(VT[self + o]);                   // agg = Vself - sum attn*Vnb
#pragma unroll
  for (int k=0;k<K_;++k)
    acc = fmaf(-(e[k]*inv), b2f(vbuf[pt][k][o]), acc);
  float hv = b2f(xTb[self + o]) + acc;
  float sc = gf[o] / sqrtf(vf[o] + 1e-5f);
  qhT[self + o] = f2b((hv - mf[o])*sc + bf_[o]);   // hT role
}

// ---------- fused MLP: 32-pt tiles, half-k hid in 16.5KB LDS, direct stores ----------
__global__ __launch_bounds__(256) void mlp_kernel(const bf16* __restrict__ hT,
                                                  const bf16* __restrict__ w1b,
                                                  const bf16* __restrict__ w2b,
                                                  const void* __restrict__ x,
                                                  const int* __restrict__ flag,
                                                  void* out)
{
  __shared__ bf16 hidh[32][264];                   // 16.5 KB (row 528B, 16B-aligned)
  int tid = threadIdx.x;
  int p0 = blockIdx.x*32;
  int lane = tid & 63, wave = tid >> 6;
  int mrow = lane & 15, quad = lane >> 4;
  bool f32o = (*flag != 0);
  int bb = p0 >> 14;                               // block never straddles b
  int tn0 = p0 & (TN-1);
  if (tid < 128) {                                 // passthrough ch 0..3 (bit copy)
    int c = tid >> 5, p = tid & 31;
    size_t si = ((size_t)bb*C_ + c)*TN + tn0 + p;
    size_t di = ((size_t)bb*132 + c)*TN + tn0 + p;
    if (f32o) ((float*)out)[di] = ((const float*)x)[si];
    else      ((bf16*)out)[di]  = ((const bf16*)x)[si];
  }
  f32x4 acc2[2][2];                                // [otile][mtile], persists both halves
#pragma unroll
  for (int oi=0;oi<2;++oi)
#pragma unroll
    for (int mt=0;mt<2;++mt) acc2[oi][mt] = (f32x4){0.f,0.f,0.f,0.f};

#pragma unroll
  for (int half = 0; half < 2; ++half) {
    if (half) __syncthreads();                     // prev stage2 reads done
    short8 am[2][4];                               // A-frags straight from global hT
#pragma unroll
    for (int mt=0;mt<2;++mt)
#pragma unroll
      for (int kq=0;kq<4;++kq)
        am[mt][kq] = *(const short8*)&hT[(size_t)(p0 + mt*16 + mrow)*C_ + kq*32 + quad*8];
#pragma unroll
    for (int oi = 0; oi < 4; ++oi) {               // wave owns 4 of this half's 16 otiles
      int ot_g = half*16 + wave*4 + oi;
      int otl  = wave*4 + oi;
      f32x4 acc[2];
#pragma unroll
      for (int mt=0;mt<2;++mt) acc[mt] = (f32x4){0.f,0.f,0.f,0.f};
#pragma unroll
      for (int kq=0;kq<4;++kq) {
        short8 bfr = *(const short8*)&w1b[(ot_g*16+mrow)*C_ + kq*32 + quad*8];
#pragma unroll
        for (int mt=0;mt<2;++mt) acc[mt] = MFMA_BF16(am[mt][kq], bfr, acc[mt]);
      }
#pragma unroll
      for (int mt=0;mt<2;++mt)
#pragma unroll
        for (int r=0;r<4;++r) {
          float z = acc[mt][r];
          hidh[mt*16 + quad*4 + r][otl*16 + mrow] = f2b(z > 0.f ? z : 0.2f*z);
        }
    }
    __syncthreads();
#pragma unroll
    for (int kc = 0; kc < 4; ++kc) {               // 4 chunks of 2 k-slices
      short8 ha[2][2];
#pragma unroll
      for (int mt=0;mt<2;++mt)
#pragma unroll
        for (int kk=0;kk<2;++kk)
          ha[mt][kk] = *(const short8*)&hidh[mt*16 + mrow][(kc*2+kk)*32 + quad*8];
#pragma unroll
      for (int oi=0;oi<2;++oi) {
        int ot2 = wave*2 + oi;                     // wave owns 2 of 8 output otiles
#pragma unroll
        for (int kk=0;kk<2;++kk) {
          int ks_g = half*8 + kc*2 + kk;
          short8 bfr = *(const short8*)&w2b[(ot2*16+mrow)*HID_ + ks_g*32 + quad*8];
#pragma unroll
          for (int mt=0;mt<2;++mt)
            acc2[oi][mt] = MFMA_BF16(ha[mt][kk], bfr, acc2[oi][mt]);
        }
      }
    }
  }
  size_t obase = (size_t)bb*132*TN;
#pragma unroll
  for (int oi=0;oi<2;++oi) {
    int ch = (wave*2+oi)*16 + mrow;
#pragma unroll
    for (int mt=0;mt<2;++mt) {
      int tn = tn0 + mt*16 + quad*4;
      size_t oidx = obase + (size_t)(4+ch)*TN + tn;
      if (f32o) {
        *(f32x4*)&((float*)out)[oidx] = acc2[oi][mt];
      } else {
        bf16 tmp[4];
#pragma unroll
        for (int r=0;r<4;++r) tmp[r] = f2b(acc2[oi][mt][r]);
        *(u64*)&((bf16*)out)[oidx] = *(u64*)tmp;
      }
    }
  }
}

extern "C" void kernel_launch(void* const* d_in, const int* in_sizes, int n_in,
                              void* d_out, int out_size, void* d_ws, size_t ws_size,
                              hipStream_t stream)
{
  (void)in_sizes; (void)n_in; (void)out_size; (void)ws_size;
  const void* x = d_in[0];
  char* ws = (char*)d_ws;
  const size_t MB = (size_t)1<<20;
  bf16*  QT  = (bf16* )(ws + 0*MB);      // 8 MB (becomes hT after attn)
  bf16*  KT  = (bf16* )(ws + 8*MB);      // 8 MB
  bf16*  VT  = (bf16* )(ws + 16*MB);     // 8 MB
  bf16*  xTb = (bf16* )(ws + 24*MB);     // 8 MB
  int*   idxw= (int*  )(ws + 32*MB);     // 2 MB
  bf16*  wqb = (bf16* )(ws + 34*MB);             // 32 KB
  bf16*  wkb = (bf16* )(ws + 34*MB + 0x8000);    // 32 KB
  bf16*  wvb = (bf16* )(ws + 34*MB + 0x10000);   // 32 KB
  bf16*  w1b = (bf16* )(ws + 34*MB + 0x18000);   // 128 KB
  bf16*  w2b = (bf16* )(ws + 34*MB + 0x38000);   // 128 KB
  float* gf  = (float*)(ws + 34*MB + 0x58000);
  float* bf_ = (float*)(ws + 34*MB + 0x58200);
  float* mf  = (float*)(ws + 34*MB + 0x58400);
  float* vf  = (float*)(ws + 34*MB + 0x58600);
  int*  flag = (int*  )(ws + 34*MB + 0x58800);

  convw_kernel  <<<dim3(706), dim3(256), 0, stream>>>(
      x, d_in[1], d_in[2], d_in[3], d_in[4], d_in[5],
      d_in[6], d_in[7], d_in[8], d_in[9],
      wqb, wkb, wvb, w1b, w2b, gf, bf_, mf, vf, flag);
  projknn_kernel<<<dim3(4608), dim3(512), 0, stream>>>(
      x, flag, wqb, wkb, wvb, xTb, QT, KT, VT, idxw);
  attn_kernel   <<<dim3(PTS/4), dim3(512), 0, stream>>>(
      idxw, xTb, QT /*->hT*/, KT, VT, gf, bf_, mf, vf);
  mlp_kernel    <<<dim3(PTS/32), dim3(256), 0, stream>>>(
      QT /*hT*/, w1b, w2b, x, flag, d_out);
}

// Round 11
// 208.065 us; speedup vs baseline: 1.0316x; 1.0316x over previous
//
#include <hip/hip_runtime.h>
#include <hip/hip_bf16.h>

typedef __hip_bfloat16 bf16;
typedef unsigned long long u64;
typedef __attribute__((ext_vector_type(8))) short short8;   // 8 bf16 = MFMA A/B frag
typedef __attribute__((ext_vector_type(4))) float f32x4;    // MFMA C/D frag

#define B_   2
#define C_   128
#define T_   32
#define N_   512
#define K_   16
#define HID_ 512
#define TN   (T_*N_)          // 16384
#define PTS  (B_*T_*N_)       // 32768

#define MFMA_BF16(a,b,c) __builtin_amdgcn_mfma_f32_16x16x32_bf16((a),(b),(c),0,0,0)

__device__ __forceinline__ float b2f(bf16 v){ return __bfloat162float(v); }
__device__ __forceinline__ bf16  f2b(float v){ return __float2bfloat16(v); }
__device__ __forceinline__ float bqf(short v){            // bf16 bits -> f32 (exact)
  return __uint_as_float(((unsigned)(unsigned short)v) << 16);
}

__device__ __forceinline__ float ldc(const void* p, int i, bool f32) {
  return f32 ? ((const float*)p)[i] : b2f(((const bf16*)p)[i]);
}

// ---------- convert weights + bn; every block locally detects input dtype; blk0 publishes flag ----------
__global__ __launch_bounds__(256) void convw_kernel(
    const void* __restrict__ x,
    const void* wq, const void* wk, const void* wv,
    const void* w1, const void* w2, const void* g, const void* bb,
    const void* m, const void* v,
    bf16* __restrict__ wqb, bf16* __restrict__ wkb, bf16* __restrict__ wvb,
    bf16* __restrict__ w1b, bf16* __restrict__ w2b,
    float* __restrict__ gf, float* __restrict__ bf_, float* __restrict__ mf,
    float* __restrict__ vf, int* __restrict__ flag)
{
  __shared__ int cnt;
  if (threadIdx.x == 0) cnt = 0;
  __syncthreads();
  const unsigned short* u = (const unsigned short*)x;
  int w = 0;
#pragma unroll
  for (int j = 0; j < 8; ++j) {
    unsigned short hv = u[threadIdx.x*8 + j];
    int e = (hv >> 7) & 0xFF;
    if (e >= 0x89) w++;
  }
  if (w) atomicAdd(&cnt, w);
  __syncthreads();
  bool f32 = (cnt > 32);
  if (blockIdx.x == 0 && threadIdx.x == 0) *flag = f32 ? 1 : 0;

  int i = blockIdx.x*256 + threadIdx.x;            // grid covers 180736 exactly
  if (i < 16384) { wqb[i] = f2b(ldc(wq, i, f32)); return; } i -= 16384;
  if (i < 16384) { wkb[i] = f2b(ldc(wk, i, f32)); return; } i -= 16384;
  if (i < 16384) { wvb[i] = f2b(ldc(wv, i, f32)); return; } i -= 16384;
  if (i < 65536) { w1b[i] = f2b(ldc(w1, i, f32)); return; } i -= 65536;
  if (i < 65536) { w2b[i] = f2b(ldc(w2, i, f32)); return; } i -= 65536;
  if (i < 128)   { gf[i]  = ldc(g, i, f32); return; }       i -= 128;
  if (i < 128)   { bf_[i] = ldc(bb, i, f32); return; }      i -= 128;
  if (i < 128)   { mf[i]  = ldc(m, i, f32); return; }       i -= 128;
  if (i < 128)   { vf[i]  = ldc(v, i, f32); return; }
}

// ---------- bitonic helpers ----------
__device__ __forceinline__ u64 shflx64(u64 v, int m) {
  return (u64)__shfl_xor((long long)v, m, 64);
}
template<int W>
__device__ __forceinline__ u64 bitonic64w(u64 key, int lane) {
#pragma unroll
  for (int k = 2; k <= W; k <<= 1) {
#pragma unroll
    for (int j = k >> 1; j >= 1; j >>= 1) {
      u64 p = shflx64(key, j);
      bool keep_min = ((lane & k) == 0) == ((lane & j) == 0);
      key = ((p < key) == keep_min) ? p : key;
    }
  }
  return key;
}
__device__ __forceinline__ unsigned bitonic32u(unsigned key, int lane) {
#pragma unroll
  for (int k = 2; k <= 64; k <<= 1) {
#pragma unroll
    for (int j = k >> 1; j >= 1; j >>= 1) {
      unsigned p = (unsigned)__shfl_xor((int)key, j, 64);
      bool keep_min = ((lane & k) == 0) == ((lane & j) == 0);
      key = ((p < key) == keep_min) ? p : key;
    }
  }
  return key;
}

// ---------- MFMA GEMM helper (32-pt tile, 8 waves, wave owns one 16-col otile) ----------
__device__ __forceinline__ void proj_gemm32(const bf16* __restrict__ W,
                                            bf16 (*ys)[136],
                                            const short8 am[2][4],
                                            int mrow, int quad, int ot)
{
  f32x4 acc[2];
#pragma unroll
  for (int mt=0;mt<2;++mt) acc[mt] = (f32x4){0.f,0.f,0.f,0.f};
#pragma unroll
  for (int kq=0;kq<4;++kq) {
    short8 bfr = *(const short8*)&W[(ot*16+mrow)*C_ + kq*32 + quad*8];
#pragma unroll
    for (int mt=0;mt<2;++mt) acc[mt] = MFMA_BF16(am[mt][kq], bfr, acc[mt]);
  }
#pragma unroll
  for (int mt=0;mt<2;++mt)
#pragma unroll
    for (int r=0;r<4;++r)
      ys[mt*16 + quad*4 + r][ot*16 + mrow] = f2b(acc[mt][r]);
}

__device__ __forceinline__ void tile_store32_512(bf16* __restrict__ dst,
                                                 const bf16 (*ys)[136], int tid)
{
  int flat = tid*8;                                // 512 thr * 8 = 4096 = 32*128
  int p = flat >> 7, c = flat & 127;
  *(short8*)&dst[(size_t)p*C_ + c] = *(const short8*)&ys[p][c];
}

// ---------- FUSED proj + knn, 28.7KB LDS union (knn occupancy preserved) ----------
// blk%5==4 -> proj block (1024, 32-pt tiles); else knn block (4096).
__global__ __launch_bounds__(512) void projknn_kernel(
    const void* __restrict__ x, const int* __restrict__ flag,
    const bf16* __restrict__ wqb, const bf16* __restrict__ wkb, const bf16* __restrict__ wvb,
    bf16* __restrict__ xTb, bf16* QT, bf16* __restrict__ KT, bf16* __restrict__ VT,
    int* __restrict__ idxout)
{
  __shared__ __align__(16) char smem[28672];       // union: knn 28672 | proj 26112
  int tid = threadIdx.x;
  int blk = blockIdx.x;
  int g = blk / 5, r = blk - g*5;
  if (r == 4) {
    // ================= proj block g ∈ [0,1024), 32 points =================
    bf16 (*xs )[136] = (bf16(*)[136])(smem);           // 8704 B (reused as ysQ)
    bf16 (*ysK)[136] = (bf16(*)[136])(smem + 8704);
    bf16 (*ysV)[136] = (bf16(*)[136])(smem + 17408);
    int p0 = g * 32;
    int b = p0 >> 14; int tn0 = p0 & (TN-1);
    if (*flag) {                                   // f32 inputs
      const float* xbase = (const float*)x + (size_t)b*C_*TN + tn0;
#pragma unroll
      for (int it=0; it<8; ++it) {
        int i = it*512 + tid;
        int c = i >> 5, p = i & 31;                // coalesced over n (128B rows)
        xs[p][c] = f2b(xbase[(size_t)c*TN + p]);
      }
    } else {                                       // bf16 inputs (bit-exact stage)
      const bf16* xbase = (const bf16*)x + (size_t)b*C_*TN + tn0;
#pragma unroll
      for (int it=0; it<8; ++it) {
        int i = it*512 + tid;
        int c = i >> 5, p = i & 31;
        xs[p][c] = xbase[(size_t)c*TN + p];
      }
    }
    __syncthreads();
    tile_store32_512(xTb + (size_t)p0*C_, xs, tid);    // point-major bf16 x
    int lane = tid & 63, wave = tid >> 6;          // 8 waves, wave = otile
    int mrow = lane & 15, quad = lane >> 4;
    short8 am[2][4];                               // A-frags (32 points = 2 mtiles)
#pragma unroll
    for (int mt=0;mt<2;++mt)
#pragma unroll
      for (int kq=0;kq<4;++kq)
        am[mt][kq] = *(const short8*)&xs[mt*16 + mrow][kq*32 + quad*8];
    __syncthreads();                               // xs reads done; xs becomes ysQ
    proj_gemm32(wqb, xs,  am, mrow, quad, wave);
    proj_gemm32(wkb, ysK, am, mrow, quad, wave);
    proj_gemm32(wvb, ysV, am, mrow, quad, wave);
    __syncthreads();
    tile_store32_512(QT + (size_t)p0*C_, xs,  tid);
    tile_store32_512(KT + (size_t)p0*C_, ysK, tid);
    tile_store32_512(VT + (size_t)p0*C_, ysV, tid);
  } else {
    // ================= knn block kblk = g*4+r ∈ [0,4096) =================
    float4* cand4 = (float4*)smem;                 // 24576 B
    u64 (*surv)[64] = (u64(*)[64])(smem + 24576);  // 4096 B
    int kblk = g*4 + r;
    int row = kblk >> 6;                           // (b,t)
    int b = row >> 5, t = row & 31;
    int ng = kblk & 63;
    bool f32 = (*flag != 0);
#pragma unroll
    for (int q = 0; q < 3; ++q) {                  // j=q time slot; 512 cols coalesced
      int tt = t - 1 + q; tt = tt < 0 ? 0 : (tt > T_-1 ? T_-1 : tt);
      size_t base = ((size_t)b*C_*T_ + tt)*(size_t)N_ + tid;   // ch0
      float c0, c1, c2;
      if (f32) {
        const float* xp = (const float*)x;
        c0 = xp[base]; c1 = xp[base + (size_t)T_*N_]; c2 = xp[base + 2*(size_t)T_*N_];
      } else {
        const bf16* xp = (const bf16*)x;
        c0 = b2f(xp[base]); c1 = b2f(xp[base + (size_t)T_*N_]); c2 = b2f(xp[base + 2*(size_t)T_*N_]);
      }
      cand4[q*N_ + tid] = make_float4(c0, c1, c2, 0.f);
    }
    __syncthreads();
    int wave = tid >> 6, lane = tid & 63;
    int n = ng*8 + wave;                           // this wave's point
    float4 a = cand4[N_ + n];                      // self (j=1 slot), broadcast read
    unsigned db[24];                               // lane owns m = lane + 64j
#pragma unroll
    for (int j = 0; j < 24; ++j) {
      float4 cm = cand4[lane + (j << 6)];          // one ds_read_b128, conflict-free
      float dx = a.x - cm.x;
      float dy = a.y - cm.y;
      float dz = a.z - cm.z;
      float d2 = __fadd_rn(__fadd_rn(__fmul_rn(dx,dx), __fmul_rn(dy,dy)), __fmul_rn(dz,dz));
      db[j] = __float_as_uint(d2);                 // d2>=0 -> u32 order == f32 order
    }
    unsigned bd = db[0];
#pragma unroll
    for (int j = 1; j < 24; ++j) bd = (db[j] < bd) ? db[j] : bd;
    unsigned sd = bitonic32u(bd, lane);
    unsigned U = (unsigned)__shfl((int)sd, 15, 64);
    int c = 0;
#pragma unroll
    for (int j = 0; j < 24; ++j) c += (db[j] <= U) ? 1 : 0;
    int sc = c;                                    // inclusive wave prefix sum
#pragma unroll
    for (int d = 1; d < 64; d <<= 1) {
      int pv = __shfl_up(sc, d, 64);
      if (lane >= d) sc += pv;
    }
    int total = __shfl(sc, 63, 64);
    int ofs = sc - c;
    u64 out16;
    if (total <= 64) {                             // ~always (E[total] ~ 18)
#pragma unroll
      for (int j = 0; j < 24; ++j) {
        if (db[j] <= U) {
          surv[wave][ofs] = ((u64)db[j] << 32) | (unsigned)(lane + (j << 6));
          ++ofs;
        }
      }
      __threadfence_block();
      u64 kk = (lane < total) ? surv[wave][lane] : ~0ull;
      out16 = (total <= 32) ? bitonic64w<32>(kk, lane)
                            : bitonic64w<64>(kk, lane); // lanes 0..15 = exact top-16
    } else {
      u64 key[24];                                 // exact fallback (rare)
#pragma unroll
      for (int j = 0; j < 24; ++j)
        key[j] = ((u64)db[j] << 32) | (unsigned)(lane + (j << 6));
      u64 res = ~0ull;
#pragma unroll 1
      for (int rr = 0; rr < 16; ++rr) {
        u64 m2 = key[0];
#pragma unroll
        for (int j = 1; j < 24; ++j) m2 = (key[j] < m2) ? key[j] : m2;
#pragma unroll
        for (int s = 32; s >= 1; s >>= 1) {
          u64 p = shflx64(m2, s);
          m2 = (p < m2) ? p : m2;
        }
        if (lane == rr) res = m2;
        int mwin = (int)(m2 & 0xffffffffu);
        int sel = ((mwin & 63) == lane) ? (mwin >> 6) : -1;
#pragma unroll
        for (int j = 0; j < 24; ++j) if (j == sel) key[j] = ~0ull;
      }
      out16 = res;
    }
    int point = (b*T_ + t)*N_ + n;
    if (lane < K_) idxout[point*K_ + lane] = (int)(out16 & 0xffffffffu);
  }
}

// ---------- attention: 4 points / 512-thread block; vectorized energy phase ----------
__global__ __launch_bounds__(512) void attn_kernel(
    const int* __restrict__ idxin, const bf16* __restrict__ xTb,
    bf16* qhT /* in: QT, out: hT */, const bf16* __restrict__ KT,
    const bf16* __restrict__ VT,
    const float* __restrict__ gf, const float* __restrict__ bf_,
    const float* __restrict__ mf, const float* __restrict__ vf)
{
  __shared__ int   col_lds[4][16];
  __shared__ float qbuf[4][C_];
  __shared__ bf16  kbuf[4][K_][136];
  __shared__ bf16  vbuf[4][K_][136];               // ~38 KB total
  __shared__ float e_lds[4][4][16];
  int tid = threadIdx.x;
  int pt = tid >> 7, o = tid & 127;
  int point = blockIdx.x*4 + pt;
  int b = point >> 14; int tn = point & (TN-1); int t = tn >> 9;
  if (o < K_) {
    int m = idxin[point*K_ + o];
    int j = m >> 9, nn = m & (N_-1);
    int tt = t-1+j; tt = tt<0?0:(tt>T_-1?T_-1:tt);
    col_lds[pt][o] = ((b*T_ + tt)*N_ + nn)*C_;
  }
  int self = point*C_;
  qbuf[pt][o] = b2f(qhT[self + o]);                // QT reads done before first sync
  __syncthreads();
  // gather 64 K/V columns per block as 16B chunks (coalesced 256B per column)
#pragma unroll
  for (int it = 0; it < 2; ++it) {
    int i = it*512 + tid;
    int pp = i >> 8, rem = i & 255, k = rem >> 4, ch = rem & 15;
    int src = col_lds[pp][k] + ch*8;
    *(short8*)&kbuf[pp][k][ch*8] = *(const short8*)&KT[src];
    *(short8*)&vbuf[pp][k][ch*8] = *(const short8*)&VT[src];
  }
  __syncthreads();
  {
    // energies: all 512 threads; thread = (point, k, head, half16)
    int pp = tid >> 7, j = tid & 127;
    int k = j >> 3, hd = (j >> 1) & 3, half = j & 1;
    const float* qp = &qbuf[pp][hd*32 + half*16];
    const bf16*  kp = &kbuf[pp][k][hd*32 + half*16];
    short8 kv0 = *(const short8*)kp;
    short8 kv1 = *(const short8*)(kp + 8);
    float qv[16];
    *(float4*)&qv[0]  = *(const float4*)(qp);
    *(float4*)&qv[4]  = *(const float4*)(qp + 4);
    *(float4*)&qv[8]  = *(const float4*)(qp + 8);
    *(float4*)&qv[12] = *(const float4*)(qp + 12);
    float e = 0.f;
#pragma unroll
    for (int i2=0;i2<8;++i2) e = fmaf(qv[i2],   bqf(kv0[i2]), e);
#pragma unroll
    for (int i2=0;i2<8;++i2) e = fmaf(qv[8+i2], bqf(kv1[i2]), e);
    e += __shfl_xor(e, 1, 64);                     // combine the two halves
    // energy = q.(Kself - Knb)/sqrt(D); self term k-constant -> dropped
    if (!half) e_lds[pp][hd][k] = -e * 0.17677669529663687f;
  }
  __syncthreads();
  int hd = o >> 5;
  float e[16]; float mx = -3e38f;
#pragma unroll
  for (int k=0;k<K_;++k){ e[k]=e_lds[pt][hd][k]; mx=fmaxf(mx,e[k]); }
  float ssum=0.f;
#pragma unroll
  for (int k=0;k<K_;++k){ e[k]=__expf(e[k]-mx); ssum+=e[k]; }
  float inv = 1.f/ssum;
  float acc = b2f(VT[self + o]);                   // agg = Vself - sum attn*Vnb
#pragma unroll
  for (int k=0;k<K_;++k)
    acc = fmaf(-(e[k]*inv), b2f(vbuf[pt][k][o]), acc);
  float hv = b2f(xTb[self + o]) + acc;
  float sc = gf[o] / sqrtf(vf[o] + 1e-5f);
  qhT[self + o] = f2b((hv - mf[o])*sc + bf_[o]);   // hT role
}

// ---------- fused MLP: 32-pt tiles, half-k hid in 16.5KB LDS, direct stores ----------
__global__ __launch_bounds__(256) void mlp_kernel(const bf16* __restrict__ hT,
                                                  const bf16* __restrict__ w1b,
                                                  const bf16* __restrict__ w2b,
                                                  const void* __restrict__ x,
                                                  const int* __restrict__ flag,
                                                  void* out)
{
  __shared__ bf16 hidh[32][264];                   // 16.5 KB (row 528B, 16B-aligned)
  int tid = threadIdx.x;
  int p0 = blockIdx.x*32;
  int lane = tid & 63, wave = tid >> 6;
  int mrow = lane & 15, quad = lane >> 4;
  bool f32o = (*flag != 0);
  int bb = p0 >> 14;                               // block never straddles b
  int tn0 = p0 & (TN-1);
  if (tid < 128) {                                 // passthrough ch 0..3 (bit copy)
    int c = tid >> 5, p = tid & 31;
    size_t si = ((size_t)bb*C_ + c)*TN + tn0 + p;
    size_t di = ((size_t)bb*132 + c)*TN + tn0 + p;
    if (f32o) ((float*)out)[di] = ((const float*)x)[si];
    else      ((bf16*)out)[di]  = ((const bf16*)x)[si];
  }
  f32x4 acc2[2][2];                                // [otile][mtile], persists both halves
#pragma unroll
  for (int oi=0;oi<2;++oi)
#pragma unroll
    for (int mt=0;mt<2;++mt) acc2[oi][mt] = (f32x4){0.f,0.f,0.f,0.f};

#pragma unroll
  for (int half = 0; half < 2; ++half) {
    if (half) __syncthreads();                     // prev stage2 reads done
    short8 am[2][4];                               // A-frags straight from global hT
#pragma unroll
    for (int mt=0;mt<2;++mt)
#pragma unroll
      for (int kq=0;kq<4;++kq)
        am[mt][kq] = *(const short8*)&hT[(size_t)(p0 + mt*16 + mrow)*C_ + kq*32 + quad*8];
#pragma unroll
    for (int oi = 0; oi < 4; ++oi) {               // wave owns 4 of this half's 16 otiles
      int ot_g = half*16 + wave*4 + oi;
      int otl  = wave*4 + oi;
      f32x4 acc[2];
#pragma unroll
      for (int mt=0;mt<2;++mt) acc[mt] = (f32x4){0.f,0.f,0.f,0.f};
#pragma unroll
      for (int kq=0;kq<4;++kq) {
        short8 bfr = *(const short8*)&w1b[(ot_g*16+mrow)*C_ + kq*32 + quad*8];
#pragma unroll
        for (int mt=0;mt<2;++mt) acc[mt] = MFMA_BF16(am[mt][kq], bfr, acc[mt]);
      }
#pragma unroll
      for (int mt=0;mt<2;++mt)
#pragma unroll
        for (int r=0;r<4;++r) {
          float z = acc[mt][r];
          hidh[mt*16 + quad*4 + r][otl*16 + mrow] = f2b(z > 0.f ? z : 0.2f*z);
        }
    }
    __syncthreads();
#pragma unroll
    for (int kc = 0; kc < 4; ++kc) {               // 4 chunks of 2 k-slices
      short8 ha[2][2];
#pragma unroll
      for (int mt=0;mt<2;++mt)
#pragma unroll
        for (int kk=0;kk<2;++kk)
          ha[mt][kk] = *(const short8*)&hidh[mt*16 + mrow][(kc*2+kk)*32 + quad*8];
#pragma unroll
      for (int oi=0;oi<2;++oi) {
        int ot2 = wave*2 + oi;                     // wave owns 2 of 8 output otiles
#pragma unroll
        for (int kk=0;kk<2;++kk) {
          int ks_g = half*8 + kc*2 + kk;
          short8 bfr = *(const short8*)&w2b[(ot2*16+mrow)*HID_ + ks_g*32 + quad*8];
#pragma unroll
          for (int mt=0;mt<2;++mt)
            acc2[oi][mt] = MFMA_BF16(ha[mt][kk], bfr, acc2[oi][mt]);
        }
      }
    }
  }
  size_t obase = (size_t)bb*132*TN;
#pragma unroll
  for (int oi=0;oi<2;++oi) {
    int ch = (wave*2+oi)*16 + mrow;
#pragma unroll
    for (int mt=0;mt<2;++mt) {
      int tn = tn0 + mt*16 + quad*4;
      size_t oidx = obase + (size_t)(4+ch)*TN + tn;
      if (f32o) {
        *(f32x4*)&((float*)out)[oidx] = acc2[oi][mt];
      } else {
        bf16 tmp[4];
#pragma unroll
        for (int r=0;r<4;++r) tmp[r] = f2b(acc2[oi][mt][r]);
        *(u64*)&((bf16*)out)[oidx] = *(u64*)tmp;
      }
    }
  }
}

extern "C" void kernel_launch(void* const* d_in, const int* in_sizes, int n_in,
                              void* d_out, int out_size, void* d_ws, size_t ws_size,
                              hipStream_t stream)
{
  (void)in_sizes; (void)n_in; (void)out_size; (void)ws_size;
  const void* x = d_in[0];
  char* ws = (char*)d_ws;
  const size_t MB = (size_t)1<<20;
  bf16*  QT  = (bf16* )(ws + 0*MB);      // 8 MB (becomes hT after attn)
  bf16*  KT  = (bf16* )(ws + 8*MB);      // 8 MB
  bf16*  VT  = (bf16* )(ws + 16*MB);     // 8 MB
  bf16*  xTb = (bf16* )(ws + 24*MB);     // 8 MB
  int*   idxw= (int*  )(ws + 32*MB);     // 2 MB
  bf16*  wqb = (bf16* )(ws + 34*MB);             // 32 KB
  bf16*  wkb = (bf16* )(ws + 34*MB + 0x8000);    // 32 KB
  bf16*  wvb = (bf16* )(ws + 34*MB + 0x10000);   // 32 KB
  bf16*  w1b = (bf16* )(ws + 34*MB + 0x18000);   // 128 KB
  bf16*  w2b = (bf16* )(ws + 34*MB + 0x38000);   // 128 KB
  float* gf  = (float*)(ws + 34*MB + 0x58000);
  float* bf_ = (float*)(ws + 34*MB + 0x58200);
  float* mf  = (float*)(ws + 34*MB + 0x58400);
  float* vf  = (float*)(ws + 34*MB + 0x58600);
  int*  flag = (int*  )(ws + 34*MB + 0x58800);

  convw_kernel  <<<dim3(706), dim3(256), 0, stream>>>(
      x, d_in[1], d_in[2], d_in[3], d_in[4], d_in[5],
      d_in[6], d_in[7], d_in[8], d_in[9],
      wqb, wkb, wvb, w1b, w2b, gf, bf_, mf, vf, flag);
  projknn_kernel<<<dim3(5120), dim3(512), 0, stream>>>(
      x, flag, wqb, wkb, wvb, xTb, QT, KT, VT, idxw);
  attn_kernel   <<<dim3(PTS/4), dim3(512), 0, stream>>>(
      idxw, xTb, QT /*->hT*/, KT, VT, gf, bf_, mf, vf);
  mlp_kernel    <<<dim3(PTS/32), dim3(256), 0, stream>>>(
      QT /*hT*/, w1b, w2b, x, flag, d_out);
}